// Round 7
// baseline (382.078 us; speedup 1.0000x reference)
//
#include <hip/hip_runtime.h>

#define BB 8
#define CC 256
#define DD 128
#define NN 4096

#define LOG2E 1.44269504f
#define MSHIFT 32.0f  // fixed softmax shift (base-2 domain); |S*log2e| << 32 always

typedef __attribute__((ext_vector_type(8))) short short8;
typedef __attribute__((ext_vector_type(4))) short short4v;
typedef __attribute__((ext_vector_type(4))) float f32x4;

static __device__ __forceinline__ unsigned short f2bf(float f) {
    unsigned u = __builtin_bit_cast(unsigned, f);
    u += 0x7FFFu + ((u >> 16) & 1u);
    return (unsigned short)(u >> 16);
}
static __device__ __forceinline__ unsigned short f2bf_trunc(float f) {
    return (unsigned short)(__builtin_bit_cast(unsigned, f) >> 16);
}
static __device__ __forceinline__ float bf2f(unsigned short h) {
    unsigned u = ((unsigned)h) << 16;
    return __builtin_bit_cast(float, u);
}
static __device__ __forceinline__ short8 pack8(float4 a, float4 b) {
    short8 r;
    r[0] = (short)f2bf(a.x); r[1] = (short)f2bf(a.y);
    r[2] = (short)f2bf(a.z); r[3] = (short)f2bf(a.w);
    r[4] = (short)f2bf(b.x); r[5] = (short)f2bf(b.y);
    r[6] = (short)f2bf(b.z); r[7] = (short)f2bf(b.w);
    return r;
}

// ---------------- kernel 1: x fp32 [b][c][n] -> xT bf16 [b][n][c] ----------------
// grid (NN/64, CC/64, BB), block 256
__global__ __launch_bounds__(256) void k_transpose_x(
        const float* __restrict__ x, unsigned short* __restrict__ xT) {
    __shared__ __align__(16) unsigned short tile[64][66];
    int nb = blockIdx.x * 64, cb = blockIdx.y * 64, b = blockIdx.z;
    const float* xp = x + (size_t)b * CC * NN;
    int t = threadIdx.x;
#pragma unroll
    for (int i = 0; i < 2; i++) {
        int idx = t + 256 * i;
        int c_l = idx >> 3;
        int n0 = (idx & 7) * 8;
        const float* src = xp + (size_t)(cb + c_l) * NN + nb + n0;
        float4 v0 = *(const float4*)(src);
        float4 v1 = *(const float4*)(src + 4);
        tile[n0 + 0][c_l] = f2bf(v0.x);
        tile[n0 + 1][c_l] = f2bf(v0.y);
        tile[n0 + 2][c_l] = f2bf(v0.z);
        tile[n0 + 3][c_l] = f2bf(v0.w);
        tile[n0 + 4][c_l] = f2bf(v1.x);
        tile[n0 + 5][c_l] = f2bf(v1.y);
        tile[n0 + 6][c_l] = f2bf(v1.z);
        tile[n0 + 7][c_l] = f2bf(v1.w);
    }
    __syncthreads();
    unsigned short* xtp = xT + (size_t)b * NN * CC;
#pragma unroll
    for (int i = 0; i < 2; i++) {
        int idx = t + 256 * i;
        int n_l = idx >> 3;
        int c0 = (idx & 7) * 8;
        const unsigned int* row = (const unsigned int*)&tile[n_l][0];
        uint4 o;
        o.x = row[(c0 >> 1) + 0];
        o.y = row[(c0 >> 1) + 1];
        o.z = row[(c0 >> 1) + 2];
        o.w = row[(c0 >> 1) + 3];
        *(uint4*)(xtp + (size_t)(nb + n_l) * CC + cb + c0) = o;
    }
}

// ---------------- kernel 2: projections (x staged in LDS; coalesced stores) ----------------
// proj 0: theta*log2e -> Q[n][d]; proj 1: phi -> K[n][d]; proj 2: g -> Vt[d][n]
// grid (NN/128, 3, BB), block 256 (4 waves; wave owns d-range wave*32..+32)
__global__ __launch_bounds__(256) void k_proj(
        const unsigned short* __restrict__ xT,
        const float* __restrict__ w_phi, const float* __restrict__ b_phi,
        const float* __restrict__ w_theta, const float* __restrict__ b_theta,
        const float* __restrict__ w_g, const float* __restrict__ b_g,
        unsigned short* __restrict__ qws, unsigned short* __restrict__ kws,
        unsigned short* __restrict__ vtws) {
    __shared__ __align__(16) unsigned short xs[128][72];     // staged x chunk [n][64c]
    __shared__ __align__(16) unsigned short rp[128][136];    // repack buffer
    int nb = blockIdx.x * 128, proj = blockIdx.y, b = blockIdx.z;
    const float *W, *bias;
    if (proj == 0) { W = w_theta; bias = b_theta; }
    else if (proj == 1) { W = w_phi; bias = b_phi; }
    else { W = w_g; bias = b_g; }
    float scl = (proj == 0) ? LOG2E : 1.0f;
    int t = threadIdx.x, lane = t & 63, wave = t >> 6;
    int l16 = lane & 15, l4 = lane >> 4;

    f32x4 acc[2][8];
#pragma unroll
    for (int mf = 0; mf < 2; mf++)
#pragma unroll
        for (int nf = 0; nf < 8; nf++)
#pragma unroll
            for (int e = 0; e < 4; e++) acc[mf][nf][e] = 0.f;

    const unsigned short* xtp = xT + (size_t)b * NN * CC;
    for (int kc = 0; kc < 4; kc++) {
        int c0k = kc * 64;
        __syncthreads();
#pragma unroll
        for (int i = 0; i < 4; i++) {  // stage [128 n][64 c]
            int idx = t + 256 * i;
            int n = idx >> 3, cc = (idx & 7) * 8;
            *(short8*)&xs[n][cc] = *(const short8*)(xtp + (size_t)(nb + n) * CC + c0k + cc);
        }
        __syncthreads();
        short8 af[2][2];
#pragma unroll
        for (int mf = 0; mf < 2; mf++)
#pragma unroll
            for (int ic = 0; ic < 2; ic++) {
                int d = wave * 32 + mf * 16 + l16;
                const float* wp = W + d * CC + c0k + ic * 32 + l4 * 8;
                af[mf][ic] = pack8(*(const float4*)wp, *(const float4*)(wp + 4));
            }
#pragma unroll
        for (int nf = 0; nf < 8; nf++)
#pragma unroll
            for (int ic = 0; ic < 2; ic++) {
                short8 bfr = *(const short8*)&xs[nf * 16 + l16][ic * 32 + l4 * 8];
                acc[0][nf] = __builtin_amdgcn_mfma_f32_16x16x32_bf16(af[0][ic], bfr, acc[0][nf], 0, 0, 0);
                acc[1][nf] = __builtin_amdgcn_mfma_f32_16x16x32_bf16(af[1][ic], bfr, acc[1][nf], 0, 0, 0);
            }
    }
    // acc C-layout: col(l16) = n-within-frag, row(l4*4+r) = d-within-frag
    __syncthreads();  // xs done; rp reuse safe
    if (proj < 2) {
        unsigned short* outp = (proj == 0 ? qws : kws) + (size_t)b * NN * DD;
#pragma unroll
        for (int mf = 0; mf < 2; mf++) {
            int d0 = wave * 32 + mf * 16 + l4 * 4;
            float bb[4];
#pragma unroll
            for (int r = 0; r < 4; r++) bb[r] = bias[d0 + r];
#pragma unroll
            for (int nf = 0; nf < 8; nf++) {
                short4v pk;
#pragma unroll
                for (int r = 0; r < 4; r++) pk[r] = (short)f2bf((acc[mf][nf][r] + bb[r]) * scl);
                *(short4v*)&rp[nf * 16 + l16][d0] = pk;
            }
        }
        __syncthreads();
#pragma unroll
        for (int i = 0; i < 8; i++) {
            int idx = t + 256 * i;
            int n = idx >> 4, dd = (idx & 15) * 8;
            *(short8*)(outp + (size_t)(nb + n) * DD + dd) = *(const short8*)&rp[n][dd];
        }
    } else {
#pragma unroll
        for (int mf = 0; mf < 2; mf++) {
            int drow = wave * 32 + mf * 16 + l4 * 4;
            float bb[4];
#pragma unroll
            for (int r = 0; r < 4; r++) bb[r] = bias[drow + r];
#pragma unroll
            for (int nf = 0; nf < 8; nf++)
#pragma unroll
                for (int r = 0; r < 4; r++)
                    rp[drow + r][nf * 16 + l16] = f2bf(acc[mf][nf][r] + bb[r]);
        }
        __syncthreads();
        unsigned short* outp = vtws + (size_t)b * DD * NN;
#pragma unroll
        for (int i = 0; i < 8; i++) {
            int idx = t + 256 * i;
            int d = idx >> 4, n0 = (idx & 15) * 8;
            *(short8*)(outp + (size_t)d * NN + nb + n0) = *(const short8*)&rp[d][n0];
        }
    }
}

// ---------------- kernel 3: flash attention — round-4 body, 512-thread block ----------------
// grid (NN/128, BB) = 256 blocks, block 512 = 2 pairs x 4 waves. Pair p covers keys
// [p*2048, +2048) in 32-key K/V tiles SHARED by its 4 waves (2x tile reuse vs round 4,
// half the staging per wave). Wave w4 owns q-rows qb + w4*32..+32 (m=2 frags).
// Fixed-max softmax p = exp2(S' - 32); cross-pair combine via LDS overlay at the end.
// LDS pooled = 58368 B -> under the ~64KiB residency granule, 2 blocks/CU = 16 waves/CU.
__global__ __launch_bounds__(512, 4) void k_flash(
        const unsigned short* __restrict__ q, const unsigned short* __restrict__ kk,
        const unsigned short* __restrict__ vt, unsigned short* __restrict__ y) {
    __shared__ __align__(16) unsigned short smem[29184];  // 58368 B pool
    unsigned short (*Kt)[32][136] = (unsigned short (*)[32][136])smem;           // 2x 32x136
    unsigned short (*Vt)[128][40] = (unsigned short (*)[128][40])(smem + 8704);  // 2x 128x40
    unsigned short (*Pt)[32][40]  = (unsigned short (*)[32][40])(smem + 18944);  // 8x 32x40

    int qb = blockIdx.x * 128, b = blockIdx.y;
    int t = threadIdx.x, lane = t & 63, wave = t >> 6;
    int pair = wave >> 2, w4 = wave & 3, tp = t & 255;
    int l16 = lane & 15, l4 = lane >> 4;
    const unsigned short* qp = q + (size_t)b * NN * DD;
    const unsigned short* kp = kk + (size_t)b * NN * DD;
    const unsigned short* vp = vt + (size_t)b * DD * NN;

    short8 qf[2][4];
#pragma unroll
    for (int m = 0; m < 2; m++) {
        int qrow = qb + w4 * 32 + m * 16 + l16;
#pragma unroll
        for (int kc = 0; kc < 4; kc++)
            qf[m][kc] = *(const short8*)(qp + (size_t)qrow * DD + kc * 32 + l4 * 8);
    }

    f32x4 o[2][8];
    float lsum[2][4];
#pragma unroll
    for (int m = 0; m < 2; m++) {
#pragma unroll
        for (int df = 0; df < 8; df++)
#pragma unroll
            for (int e = 0; e < 4; e++) o[m][df][e] = 0.f;
#pragma unroll
        for (int r = 0; r < 4; r++) lsum[m][r] = 0.f;
    }

    int kbase = pair * (NN / 2);
    for (int it = 0; it < (NN / 2) / 32; ++it) {
        int mb = kbase + it * 32;
        __syncthreads();
#pragma unroll
        for (int i = 0; i < 2; i++) {  // stage K tile [32 keys][128 d] (pair-shared)
            int idx = tp + 256 * i;
            int mr = idx >> 4, d0 = (idx & 15) * 8;
            *(short8*)&Kt[pair][mr][d0] = *(const short8*)(kp + (size_t)(mb + mr) * DD + d0);
        }
#pragma unroll
        for (int i = 0; i < 2; i++) {  // stage V^T tile [128 d][32 keys]
            int idx = tp + 256 * i;
            int dr = idx >> 2, m0 = (idx & 3) * 8;
            *(short8*)&Vt[pair][dr][m0] = *(const short8*)(vp + (size_t)dr * NN + mb + m0);
        }
        __syncthreads();

        // S' = Q' K^T - 32  (32 q-rows x 32 keys per wave)
        f32x4 s[2][2];
#pragma unroll
        for (int m = 0; m < 2; m++)
#pragma unroll
            for (int nf = 0; nf < 2; nf++)
#pragma unroll
                for (int e = 0; e < 4; e++) s[m][nf][e] = -MSHIFT;
#pragma unroll
        for (int kc = 0; kc < 4; kc++)
#pragma unroll
            for (int nf = 0; nf < 2; nf++) {
                short8 bfr = *(const short8*)&Kt[pair][nf * 16 + l16][kc * 32 + l4 * 8];
                s[0][nf] = __builtin_amdgcn_mfma_f32_16x16x32_bf16(qf[0][kc], bfr, s[0][nf], 0, 0, 0);
                s[1][nf] = __builtin_amdgcn_mfma_f32_16x16x32_bf16(qf[1][kc], bfr, s[1][nf], 0, 0, 0);
            }

        // p = exp2(s'); per-lane row partials; P -> LDS (trunc-to-bf16: bias cancels in ratio)
#pragma unroll
        for (int m = 0; m < 2; m++)
#pragma unroll
            for (int nf = 0; nf < 2; nf++)
#pragma unroll
                for (int r = 0; r < 4; r++) {
                    float p = __builtin_exp2f(s[m][nf][r]);
                    lsum[m][r] += p;
                    Pt[wave][m * 16 + l4 * 4 + r][nf * 16 + l16] = f2bf_trunc(p);
                }
        asm volatile("s_waitcnt lgkmcnt(0)" ::: "memory");

        // O += P V  (k = 32 keys in a single MFMA K-dim)
        short8 pa0 = *(const short8*)&Pt[wave][l16][l4 * 8];
        short8 pa1 = *(const short8*)&Pt[wave][16 + l16][l4 * 8];
#pragma unroll
        for (int df = 0; df < 8; df++) {
            short8 vb = *(const short8*)&Vt[pair][df * 16 + l16][l4 * 8];
            o[0][df] = __builtin_amdgcn_mfma_f32_16x16x32_bf16(pa0, vb, o[0][df], 0, 0, 0);
            o[1][df] = __builtin_amdgcn_mfma_f32_16x16x32_bf16(pa1, vb, o[1][df], 0, 0, 0);
        }
    }

    // ---- cross-pair combine; Ox[128][136] + Ls[128] overlay the Kt/Vt pool ----
    __syncthreads();
    unsigned short (*Ox)[136] = (unsigned short (*)[136])smem;   // 17408 shorts
    float* Ls = (float*)(smem + 17408);                          // 128 floats
    int rb = w4 * 32;
    if (pair == 1) {
#pragma unroll
        for (int m = 0; m < 2; m++) {
#pragma unroll
            for (int df = 0; df < 8; df++)
#pragma unroll
                for (int r = 0; r < 4; r++)
                    Ox[rb + m * 16 + l4 * 4 + r][df * 16 + l16] = f2bf(o[m][df][r]);
#pragma unroll
            for (int r = 0; r < 4; r++) {
                float v = lsum[m][r];
                v += __shfl_xor(v, 1);
                v += __shfl_xor(v, 2);
                v += __shfl_xor(v, 4);
                v += __shfl_xor(v, 8);
                if (l16 == 0) Ls[rb + m * 16 + l4 * 4 + r] = v;
            }
        }
    }
    __syncthreads();
    if (pair == 0) {
#pragma unroll
        for (int m = 0; m < 2; m++)
#pragma unroll
            for (int r = 0; r < 4; r++) {
                float v = lsum[m][r];
                v += __shfl_xor(v, 1);
                v += __shfl_xor(v, 2);
                v += __shfl_xor(v, 4);
                v += __shfl_xor(v, 8);
                int row = rb + m * 16 + l4 * 4 + r;
                float inv = 1.0f / (v + Ls[row]);
#pragma unroll
                for (int df = 0; df < 8; df++) {
                    int col = df * 16 + l16;
                    Ox[row][col] = f2bf((o[m][df][r] + bf2f(Ox[row][col])) * inv);
                }
            }
    }
    __syncthreads();
    unsigned short* yp = y + (size_t)b * NN * DD;
#pragma unroll
    for (int i = 0; i < 4; i++) {
        int idx = t + 512 * i;
        int nr = idx >> 4, d0 = (idx & 15) * 8;
        *(short8*)(yp + (size_t)(qb + nr) * DD + d0) = *(const short8*)&Ox[nr][d0];
    }
}

// ---------------- kernel 4: out = w_mask . y^T + b_mask + x (fp32 out) ----------------
// grid (NN/64, BB), block 256 (wave owns c-range wave*64..+64, n 64)
__global__ __launch_bounds__(256) void k_maskout(
        const unsigned short* __restrict__ y, const float* __restrict__ w_mask,
        const float* __restrict__ b_mask, const float* __restrict__ x,
        float* __restrict__ out) {
    __shared__ __align__(16) unsigned short Ys[64][136];
    int nb = blockIdx.x * 64, b = blockIdx.y;
    int t = threadIdx.x, lane = t & 63, wave = t >> 6;
    int l16 = lane & 15, l4 = lane >> 4;

    const unsigned short* yp = y + (size_t)b * NN * DD;
#pragma unroll
    for (int i = 0; i < 4; i++) {
        int idx = t + 256 * i;
        int nr = idx >> 4, d0 = (idx & 15) * 8;
        *(short8*)&Ys[nr][d0] = *(const short8*)(yp + (size_t)(nb + nr) * DD + d0);
    }
    __syncthreads();

    f32x4 acc[4][4];
#pragma unroll
    for (int mf = 0; mf < 4; mf++)
#pragma unroll
        for (int nf = 0; nf < 4; nf++)
#pragma unroll
            for (int e = 0; e < 4; e++) acc[mf][nf][e] = 0.f;

#pragma unroll
    for (int kc = 0; kc < 4; kc++) {
        int d0 = kc * 32 + l4 * 8;
        short8 af[4];
#pragma unroll
        for (int mf = 0; mf < 4; mf++) {
            int c = wave * 64 + mf * 16 + l16;
            const float* wp = w_mask + c * DD + d0;
            af[mf] = pack8(*(const float4*)wp, *(const float4*)(wp + 4));
        }
#pragma unroll
        for (int nf = 0; nf < 4; nf++) {
            short8 bfr = *(const short8*)&Ys[nf * 16 + l16][d0];
#pragma unroll
            for (int mf = 0; mf < 4; mf++)
                acc[mf][nf] = __builtin_amdgcn_mfma_f32_16x16x32_bf16(af[mf], bfr, acc[mf][nf], 0, 0, 0);
        }
    }

    const float* xp = x + (size_t)b * CC * NN;
    float* op = out + (size_t)b * CC * NN;
#pragma unroll
    for (int mf = 0; mf < 4; mf++) {
        int c0 = wave * 64 + mf * 16 + l4 * 4;
        float bb[4];
#pragma unroll
        for (int r = 0; r < 4; r++) bb[r] = b_mask[c0 + r];
#pragma unroll
        for (int r = 0; r < 4; r++) {
            size_t rowoff = (size_t)(c0 + r) * NN;
#pragma unroll
            for (int nf = 0; nf < 4; nf++) {
                int n = nb + nf * 16 + l16;
                op[rowoff + n] = acc[mf][nf][r] + bb[r] + xp[rowoff + n];
            }
        }
    }
}

extern "C" void kernel_launch(void* const* d_in, const int* in_sizes, int n_in,
                              void* d_out, int out_size, void* d_ws, size_t ws_size,
                              hipStream_t stream) {
    const float* x       = (const float*)d_in[0];
    const float* w_phi   = (const float*)d_in[1];
    const float* b_phi   = (const float*)d_in[2];
    const float* w_theta = (const float*)d_in[3];
    const float* b_theta = (const float*)d_in[4];
    const float* w_g     = (const float*)d_in[5];
    const float* b_g     = (const float*)d_in[6];
    const float* w_mask  = (const float*)d_in[7];
    const float* b_mask  = (const float*)d_in[8];
    float* out = (float*)d_out;

    // ws layout (bytes): xT 16MiB | Q 8MiB | K 8MiB | Vt 8MiB | y 8MiB = 48MiB (bf16)
    char* ws = (char*)d_ws;
    unsigned short* xT  = (unsigned short*)(ws);
    unsigned short* qw  = (unsigned short*)(ws + ((size_t)16 << 20));
    unsigned short* kw  = (unsigned short*)(ws + ((size_t)24 << 20));
    unsigned short* vtw = (unsigned short*)(ws + ((size_t)32 << 20));
    unsigned short* yw  = (unsigned short*)(ws + ((size_t)40 << 20));

    k_transpose_x<<<dim3(NN / 64, CC / 64, BB), 256, 0, stream>>>(x, xT);
    k_proj<<<dim3(NN / 128, 3, BB), 256, 0, stream>>>(xT, w_phi, b_phi, w_theta, b_theta,
                                                      w_g, b_g, qw, kw, vtw);
    k_flash<<<dim3(NN / 128, BB), 512, 0, stream>>>(qw, kw, vtw, yw);
    k_maskout<<<dim3(NN / 64, BB), 256, 0, stream>>>(yw, w_mask, b_mask, x, out);
}

// Round 8
// 271.469 us; speedup vs baseline: 1.4074x; 1.4074x over previous
//
#include <hip/hip_runtime.h>

#define BB 8
#define CC 256
#define DD 128
#define NN 4096

#define LOG2E 1.44269504f
#define MSHIFT 32.0f  // fixed softmax shift (base-2 domain); |S*log2e| << 32 always

typedef __attribute__((ext_vector_type(8))) short short8;
typedef __attribute__((ext_vector_type(4))) short short4v;
typedef __attribute__((ext_vector_type(4))) float f32x4;

static __device__ __forceinline__ unsigned short f2bf(float f) {
    unsigned u = __builtin_bit_cast(unsigned, f);
    u += 0x7FFFu + ((u >> 16) & 1u);
    return (unsigned short)(u >> 16);
}
static __device__ __forceinline__ unsigned short f2bf_trunc(float f) {
    return (unsigned short)(__builtin_bit_cast(unsigned, f) >> 16);
}
static __device__ __forceinline__ float bf2f(unsigned short h) {
    unsigned u = ((unsigned)h) << 16;
    return __builtin_bit_cast(float, u);
}
static __device__ __forceinline__ short8 pack8(float4 a, float4 b) {
    short8 r;
    r[0] = (short)f2bf(a.x); r[1] = (short)f2bf(a.y);
    r[2] = (short)f2bf(a.z); r[3] = (short)f2bf(a.w);
    r[4] = (short)f2bf(b.x); r[5] = (short)f2bf(b.y);
    r[6] = (short)f2bf(b.z); r[7] = (short)f2bf(b.w);
    return r;
}

// ---------------- kernel 1: x fp32 [b][c][n] -> xT bf16 [b][n][c] ----------------
// grid (NN/64, CC/64, BB), block 256
__global__ __launch_bounds__(256) void k_transpose_x(
        const float* __restrict__ x, unsigned short* __restrict__ xT) {
    __shared__ __align__(16) unsigned short tile[64][66];
    int nb = blockIdx.x * 64, cb = blockIdx.y * 64, b = blockIdx.z;
    const float* xp = x + (size_t)b * CC * NN;
    int t = threadIdx.x;
#pragma unroll
    for (int i = 0; i < 2; i++) {
        int idx = t + 256 * i;
        int c_l = idx >> 3;
        int n0 = (idx & 7) * 8;
        const float* src = xp + (size_t)(cb + c_l) * NN + nb + n0;
        float4 v0 = *(const float4*)(src);
        float4 v1 = *(const float4*)(src + 4);
        tile[n0 + 0][c_l] = f2bf(v0.x);
        tile[n0 + 1][c_l] = f2bf(v0.y);
        tile[n0 + 2][c_l] = f2bf(v0.z);
        tile[n0 + 3][c_l] = f2bf(v0.w);
        tile[n0 + 4][c_l] = f2bf(v1.x);
        tile[n0 + 5][c_l] = f2bf(v1.y);
        tile[n0 + 6][c_l] = f2bf(v1.z);
        tile[n0 + 7][c_l] = f2bf(v1.w);
    }
    __syncthreads();
    unsigned short* xtp = xT + (size_t)b * NN * CC;
#pragma unroll
    for (int i = 0; i < 2; i++) {
        int idx = t + 256 * i;
        int n_l = idx >> 3;
        int c0 = (idx & 7) * 8;
        const unsigned int* row = (const unsigned int*)&tile[n_l][0];
        uint4 o;
        o.x = row[(c0 >> 1) + 0];
        o.y = row[(c0 >> 1) + 1];
        o.z = row[(c0 >> 1) + 2];
        o.w = row[(c0 >> 1) + 3];
        *(uint4*)(xtp + (size_t)(nb + n_l) * CC + cb + c0) = o;
    }
}

// ---------------- kernel 2: projections (x staged in LDS; coalesced stores) ----------------
// proj 0: theta*log2e -> Q[n][d]; proj 1: phi -> K[n][d]; proj 2: g -> Vt[d][n]
// grid (NN/128, 3, BB), block 256 (4 waves; wave owns d-range wave*32..+32)
__global__ __launch_bounds__(256) void k_proj(
        const unsigned short* __restrict__ xT,
        const float* __restrict__ w_phi, const float* __restrict__ b_phi,
        const float* __restrict__ w_theta, const float* __restrict__ b_theta,
        const float* __restrict__ w_g, const float* __restrict__ b_g,
        unsigned short* __restrict__ qws, unsigned short* __restrict__ kws,
        unsigned short* __restrict__ vtws) {
    __shared__ __align__(16) unsigned short xs[128][72];     // staged x chunk [n][64c]
    __shared__ __align__(16) unsigned short rp[128][136];    // repack buffer
    int nb = blockIdx.x * 128, proj = blockIdx.y, b = blockIdx.z;
    const float *W, *bias;
    if (proj == 0) { W = w_theta; bias = b_theta; }
    else if (proj == 1) { W = w_phi; bias = b_phi; }
    else { W = w_g; bias = b_g; }
    float scl = (proj == 0) ? LOG2E : 1.0f;
    int t = threadIdx.x, lane = t & 63, wave = t >> 6;
    int l16 = lane & 15, l4 = lane >> 4;

    f32x4 acc[2][8];
#pragma unroll
    for (int mf = 0; mf < 2; mf++)
#pragma unroll
        for (int nf = 0; nf < 8; nf++)
#pragma unroll
            for (int e = 0; e < 4; e++) acc[mf][nf][e] = 0.f;

    const unsigned short* xtp = xT + (size_t)b * NN * CC;
    for (int kc = 0; kc < 4; kc++) {
        int c0k = kc * 64;
        __syncthreads();
#pragma unroll
        for (int i = 0; i < 4; i++) {  // stage [128 n][64 c]
            int idx = t + 256 * i;
            int n = idx >> 3, cc = (idx & 7) * 8;
            *(short8*)&xs[n][cc] = *(const short8*)(xtp + (size_t)(nb + n) * CC + c0k + cc);
        }
        __syncthreads();
        short8 af[2][2];
#pragma unroll
        for (int mf = 0; mf < 2; mf++)
#pragma unroll
            for (int ic = 0; ic < 2; ic++) {
                int d = wave * 32 + mf * 16 + l16;
                const float* wp = W + d * CC + c0k + ic * 32 + l4 * 8;
                af[mf][ic] = pack8(*(const float4*)wp, *(const float4*)(wp + 4));
            }
#pragma unroll
        for (int nf = 0; nf < 8; nf++)
#pragma unroll
            for (int ic = 0; ic < 2; ic++) {
                short8 bfr = *(const short8*)&xs[nf * 16 + l16][ic * 32 + l4 * 8];
                acc[0][nf] = __builtin_amdgcn_mfma_f32_16x16x32_bf16(af[0][ic], bfr, acc[0][nf], 0, 0, 0);
                acc[1][nf] = __builtin_amdgcn_mfma_f32_16x16x32_bf16(af[1][ic], bfr, acc[1][nf], 0, 0, 0);
            }
    }
    // acc C-layout: col(l16) = n-within-frag, row(l4*4+r) = d-within-frag
    __syncthreads();  // xs done; rp reuse safe
    if (proj < 2) {
        unsigned short* outp = (proj == 0 ? qws : kws) + (size_t)b * NN * DD;
#pragma unroll
        for (int mf = 0; mf < 2; mf++) {
            int d0 = wave * 32 + mf * 16 + l4 * 4;
            float bb[4];
#pragma unroll
            for (int r = 0; r < 4; r++) bb[r] = bias[d0 + r];
#pragma unroll
            for (int nf = 0; nf < 8; nf++) {
                short4v pk;
#pragma unroll
                for (int r = 0; r < 4; r++) pk[r] = (short)f2bf((acc[mf][nf][r] + bb[r]) * scl);
                *(short4v*)&rp[nf * 16 + l16][d0] = pk;
            }
        }
        __syncthreads();
#pragma unroll
        for (int i = 0; i < 8; i++) {
            int idx = t + 256 * i;
            int n = idx >> 4, dd = (idx & 15) * 8;
            *(short8*)(outp + (size_t)(nb + n) * DD + dd) = *(const short8*)&rp[n][dd];
        }
    } else {
#pragma unroll
        for (int mf = 0; mf < 2; mf++) {
            int drow = wave * 32 + mf * 16 + l4 * 4;
            float bb[4];
#pragma unroll
            for (int r = 0; r < 4; r++) bb[r] = bias[drow + r];
#pragma unroll
            for (int nf = 0; nf < 8; nf++)
#pragma unroll
                for (int r = 0; r < 4; r++)
                    rp[drow + r][nf * 16 + l16] = f2bf(acc[mf][nf][r] + bb[r]);
        }
        __syncthreads();
        unsigned short* outp = vtws + (size_t)b * DD * NN;
#pragma unroll
        for (int i = 0; i < 8; i++) {
            int idx = t + 256 * i;
            int d = idx >> 4, n0 = (idx & 15) * 8;
            *(short8*)(outp + (size_t)d * NN + nb + n0) = *(const short8*)&rp[d][n0];
        }
    }
}

// ---------------- kernel 3: flash attention — r4 body, 2-wave / 24 KB blocks ----------------
// grid (NN/64, 2, BB) = 1024 blocks, block 128 = 2 waves sharing ONE 32-key K/V tile.
// Block (qt, ks, b): keys [ks*2048, +2048), 64 iters. Wave w owns q-rows qb + w*32..+32.
// LDS = 24064 B -> ~5 blocks/CU resident (10 waves) under the ~128 KiB usable-LDS cap.
// Fixed-max softmax p = exp2(S' - 32); emits UNNORMALIZED O-partial (bf16) + row-sums;
// k_maskout combines the 2 ks-partials by addition.
__global__ __launch_bounds__(128, 4) void k_flash(
        const unsigned short* __restrict__ q, const unsigned short* __restrict__ kk,
        const unsigned short* __restrict__ vt, unsigned short* __restrict__ opart,
        float* __restrict__ lsums) {
    __shared__ __align__(16) unsigned short smem[12032];  // 24064 B pool
    unsigned short (*Kt)[136] = (unsigned short (*)[136])smem;            // 32x136  8704 B
    unsigned short (*Vt)[40]  = (unsigned short (*)[40])(smem + 4352);    // 128x40 10240 B
    unsigned short (*Pt)[32][40] = (unsigned short (*)[32][40])(smem + 9472);  // 2x32x40

    int qb = blockIdx.x * 64, ks = blockIdx.y, b = blockIdx.z;
    int t = threadIdx.x, lane = t & 63, wave = t >> 6;
    int l16 = lane & 15, l4 = lane >> 4;
    const unsigned short* qp = q + (size_t)b * NN * DD;
    const unsigned short* kp = kk + (size_t)b * NN * DD;
    const unsigned short* vp = vt + (size_t)b * DD * NN;

    short8 qf[2][4];
#pragma unroll
    for (int m = 0; m < 2; m++) {
        int qrow = qb + wave * 32 + m * 16 + l16;
#pragma unroll
        for (int kc = 0; kc < 4; kc++)
            qf[m][kc] = *(const short8*)(qp + (size_t)qrow * DD + kc * 32 + l4 * 8);
    }

    f32x4 o[2][8];
    float lsum[2][4];
#pragma unroll
    for (int m = 0; m < 2; m++) {
#pragma unroll
        for (int df = 0; df < 8; df++)
#pragma unroll
            for (int e = 0; e < 4; e++) o[m][df][e] = 0.f;
#pragma unroll
        for (int r = 0; r < 4; r++) lsum[m][r] = 0.f;
    }

    int kbase = ks * (NN / 2);
    for (int it = 0; it < (NN / 2) / 32; ++it) {
        int mb = kbase + it * 32;
        __syncthreads();
#pragma unroll
        for (int i = 0; i < 4; i++) {  // stage K tile [32 keys][128 d] (block-shared)
            int idx = t + 128 * i;
            int mr = idx >> 4, d0 = (idx & 15) * 8;
            *(short8*)&Kt[mr][d0] = *(const short8*)(kp + (size_t)(mb + mr) * DD + d0);
        }
#pragma unroll
        for (int i = 0; i < 4; i++) {  // stage V^T tile [128 d][32 keys]
            int idx = t + 128 * i;
            int dr = idx >> 2, m0 = (idx & 3) * 8;
            *(short8*)&Vt[dr][m0] = *(const short8*)(vp + (size_t)dr * NN + mb + m0);
        }
        __syncthreads();

        // S' = Q' K^T - 32  (32 q-rows x 32 keys per wave)
        f32x4 s[2][2];
#pragma unroll
        for (int m = 0; m < 2; m++)
#pragma unroll
            for (int nf = 0; nf < 2; nf++)
#pragma unroll
                for (int e = 0; e < 4; e++) s[m][nf][e] = -MSHIFT;
#pragma unroll
        for (int kc = 0; kc < 4; kc++)
#pragma unroll
            for (int nf = 0; nf < 2; nf++) {
                short8 bfr = *(const short8*)&Kt[nf * 16 + l16][kc * 32 + l4 * 8];
                s[0][nf] = __builtin_amdgcn_mfma_f32_16x16x32_bf16(qf[0][kc], bfr, s[0][nf], 0, 0, 0);
                s[1][nf] = __builtin_amdgcn_mfma_f32_16x16x32_bf16(qf[1][kc], bfr, s[1][nf], 0, 0, 0);
            }

        // p = exp2(s'); per-lane row partials; P -> LDS (trunc-to-bf16: bias cancels in ratio)
#pragma unroll
        for (int m = 0; m < 2; m++)
#pragma unroll
            for (int nf = 0; nf < 2; nf++)
#pragma unroll
                for (int r = 0; r < 4; r++) {
                    float p = __builtin_exp2f(s[m][nf][r]);
                    lsum[m][r] += p;
                    Pt[wave][m * 16 + l4 * 4 + r][nf * 16 + l16] = f2bf_trunc(p);
                }
        asm volatile("s_waitcnt lgkmcnt(0)" ::: "memory");

        // O += P V  (k = 32 keys in a single MFMA K-dim)
        short8 pa0 = *(const short8*)&Pt[wave][l16][l4 * 8];
        short8 pa1 = *(const short8*)&Pt[wave][16 + l16][l4 * 8];
#pragma unroll
        for (int df = 0; df < 8; df++) {
            short8 vb = *(const short8*)&Vt[df * 16 + l16][l4 * 8];
            o[0][df] = __builtin_amdgcn_mfma_f32_16x16x32_bf16(pa0, vb, o[0][df], 0, 0, 0);
            o[1][df] = __builtin_amdgcn_mfma_f32_16x16x32_bf16(pa1, vb, o[1][df], 0, 0, 0);
        }
    }

    // ---- epilogue (UNNORMALIZED partial): Ox[64][136] + Ls[64] overlay the pool ----
    __syncthreads();
    unsigned short (*Ox)[136] = (unsigned short (*)[136])smem;   // 17408 B
    float* Ls = (float*)((char*)smem + 17408);                   // 256 B
    int rb = wave * 32;
#pragma unroll
    for (int m = 0; m < 2; m++) {
#pragma unroll
        for (int df = 0; df < 8; df++)
#pragma unroll
            for (int r = 0; r < 4; r++)
                Ox[rb + m * 16 + l4 * 4 + r][df * 16 + l16] = f2bf(o[m][df][r]);
#pragma unroll
        for (int r = 0; r < 4; r++) {
            float v = lsum[m][r];
            v += __shfl_xor(v, 1);
            v += __shfl_xor(v, 2);
            v += __shfl_xor(v, 4);
            v += __shfl_xor(v, 8);
            if (l16 == 0) Ls[rb + m * 16 + l4 * 4 + r] = v;
        }
    }
    __syncthreads();
    unsigned short* op = opart + (((size_t)ks * BB + b) * NN + qb) * DD;
#pragma unroll
    for (int i = 0; i < 8; i++) {
        int idx = t + 128 * i;
        int nr = idx >> 4, d0 = (idx & 15) * 8;
        *(short8*)(op + (size_t)nr * DD + d0) = *(const short8*)&Ox[nr][d0];
    }
    if (t < 64) lsums[((size_t)ks * BB + b) * NN + qb + t] = Ls[t];
}

// ---------------- kernel 4: combine partials + out = w_mask . y^T + b_mask + x ----------------
// grid (NN/64, 2, BB), block 256; cs = blockIdx.y picks c-range cs*128..+128
__global__ __launch_bounds__(256) void k_maskout(
        const unsigned short* __restrict__ opart, const float* __restrict__ lsums,
        const float* __restrict__ w_mask, const float* __restrict__ b_mask,
        const float* __restrict__ x, float* __restrict__ out) {
    __shared__ __align__(16) unsigned short Ys[64][136];
    __shared__ float invl[64];
    int nb = blockIdx.x * 64, cs = blockIdx.y, b = blockIdx.z;
    int t = threadIdx.x, lane = t & 63, wave = t >> 6;
    int l16 = lane & 15, l4 = lane >> 4;

    const unsigned short* o0 = opart + ((size_t)b * NN + nb) * DD;
    const unsigned short* o1 = opart + (((size_t)BB + b) * NN + nb) * DD;
    if (t < 64) {
        float ls0 = lsums[(size_t)b * NN + nb + t];
        float ls1 = lsums[((size_t)BB + b) * NN + nb + t];
        invl[t] = 1.0f / (ls0 + ls1);
    }
    __syncthreads();
#pragma unroll
    for (int i = 0; i < 4; i++) {  // combine the 2 key-split partials while staging y
        int idx = t + 256 * i;
        int nr = idx >> 4, d0 = (idx & 15) * 8;
        short8 a = *(const short8*)(o0 + (size_t)nr * DD + d0);
        short8 c = *(const short8*)(o1 + (size_t)nr * DD + d0);
        float inv = invl[nr];
        short8 yv;
#pragma unroll
        for (int j = 0; j < 8; j++)
            yv[j] = (short)f2bf((bf2f((unsigned short)a[j]) + bf2f((unsigned short)c[j])) * inv);
        *(short8*)&Ys[nr][d0] = yv;
    }
    __syncthreads();

    f32x4 acc[2][4];
#pragma unroll
    for (int mf = 0; mf < 2; mf++)
#pragma unroll
        for (int nf = 0; nf < 4; nf++)
#pragma unroll
            for (int e = 0; e < 4; e++) acc[mf][nf][e] = 0.f;

#pragma unroll
    for (int kc = 0; kc < 4; kc++) {
        int d0 = kc * 32 + l4 * 8;
        short8 af[2];
#pragma unroll
        for (int mf = 0; mf < 2; mf++) {
            int c = cs * 128 + wave * 32 + mf * 16 + l16;
            const float* wp = w_mask + c * DD + d0;
            af[mf] = pack8(*(const float4*)wp, *(const float4*)(wp + 4));
        }
#pragma unroll
        for (int nf = 0; nf < 4; nf++) {
            short8 bfr = *(const short8*)&Ys[nf * 16 + l16][d0];
#pragma unroll
            for (int mf = 0; mf < 2; mf++)
                acc[mf][nf] = __builtin_amdgcn_mfma_f32_16x16x32_bf16(af[mf], bfr, acc[mf][nf], 0, 0, 0);
        }
    }

    const float* xp = x + (size_t)b * CC * NN;
    float* op = out + (size_t)b * CC * NN;
#pragma unroll
    for (int mf = 0; mf < 2; mf++) {
        int c0 = cs * 128 + wave * 32 + mf * 16 + l4 * 4;
        float bb[4];
#pragma unroll
        for (int r = 0; r < 4; r++) bb[r] = b_mask[c0 + r];
#pragma unroll
        for (int r = 0; r < 4; r++) {
            size_t rowoff = (size_t)(c0 + r) * NN;
#pragma unroll
            for (int nf = 0; nf < 4; nf++) {
                int n = nb + nf * 16 + l16;
                op[rowoff + n] = acc[mf][nf][r] + bb[r] + xp[rowoff + n];
            }
        }
    }
}

extern "C" void kernel_launch(void* const* d_in, const int* in_sizes, int n_in,
                              void* d_out, int out_size, void* d_ws, size_t ws_size,
                              hipStream_t stream) {
    const float* x       = (const float*)d_in[0];
    const float* w_phi   = (const float*)d_in[1];
    const float* b_phi   = (const float*)d_in[2];
    const float* w_theta = (const float*)d_in[3];
    const float* b_theta = (const float*)d_in[4];
    const float* w_g     = (const float*)d_in[5];
    const float* b_g     = (const float*)d_in[6];
    const float* w_mask  = (const float*)d_in[7];
    const float* b_mask  = (const float*)d_in[8];
    float* out = (float*)d_out;

    // ws (48 MiB): [0,16M): xT (dead after k_proj) -> reused as Opart (2*8*4096*128 bf16 = 16 MiB)
    //              [16,24M): Q | [24,32M): K | [32,40M): Vt | [40M+): lsums (2*8*4096 fp32 = 256 KiB)
    char* ws = (char*)d_ws;
    unsigned short* xT    = (unsigned short*)(ws);
    unsigned short* opart = (unsigned short*)(ws);  // overlays xT after proj
    unsigned short* qw    = (unsigned short*)(ws + ((size_t)16 << 20));
    unsigned short* kw    = (unsigned short*)(ws + ((size_t)24 << 20));
    unsigned short* vtw   = (unsigned short*)(ws + ((size_t)32 << 20));
    float*          lsums = (float*)(ws + ((size_t)40 << 20));

    k_transpose_x<<<dim3(NN / 64, CC / 64, BB), 256, 0, stream>>>(x, xT);
    k_proj<<<dim3(NN / 128, 3, BB), 256, 0, stream>>>(xT, w_phi, b_phi, w_theta, b_theta,
                                                      w_g, b_g, qw, kw, vtw);
    k_flash<<<dim3(NN / 64, 2, BB), 128, 0, stream>>>(qw, kw, vtw, opart, lsums);
    k_maskout<<<dim3(NN / 64, 2, BB), 256, 0, stream>>>(opart, lsums, w_mask, b_mask, x, out);
}